// Round 5
// baseline (827.343 us; speedup 1.0000x reference)
//
#include <hip/hip_runtime.h>
#include <hip/hip_fp16.h>

#define N_NODES 50000
#define N_EDGES 800000
#define IN_DIM  64
#define OUT_DIM 32
#define FEAT    64                   // B*OUT per node, node-major [N][B][OUT]
#define NODES_PER_BIN 32
#define NBINS   ((N_NODES + NODES_PER_BIN - 1) / NODES_PER_BIN)   // 1563
#define BIN_CAP 768                  // mean 512, sigma ~23 -> +11 sigma
#define SCATTER_BLOCKS (N_EDGES / 256)            // 3125 (exact)
#define FC_NODES_PER_BLOCK 8
#define FC_BLOCKS (N_NODES / FC_NODES_PER_BLOCK)  // 6250 (exact)

// Fused K1.
//  blocks [0,SCATTER_BLOCKS): bin edges by dst>>5 with per-bin atomic cursors.
//    Sequential append per bin => write frontier is ~1563 hot lines (L2-resident),
//    so lines fill before eviction (kills R4's 51 MB line-thrash).
//    Record: src(16b) | dst&31 (5b) | weight quantized to 11b.
//  blocks [SCATTER_BLOCKS, +FC_BLOCKS): fc for 8 nodes/block.
//    z = h@Wfc + bfc -> ezh = exp(z) in fp16, and per-(n,b) attention scalars
//    a_tab[n] = (a_s[n,0], a_d[n,0], a_s[n,1], a_d[n,1]).
__global__ __launch_bounds__(256) void fused_fc_scatter_kernel(
    const float* __restrict__ h, const float* __restrict__ Wfc,
    const float* __restrict__ bfc, const float* __restrict__ Watt,
    const int* __restrict__ src, const int* __restrict__ dst,
    const float* __restrict__ weight,
    __half* __restrict__ ezh, float4* __restrict__ a_tab,
    int* __restrict__ cursor, unsigned int* __restrict__ payload) {
  __shared__ float Wl[IN_DIM * OUT_DIM];               // 8 KB
  __shared__ float4 hs4[FC_NODES_PER_BLOCK][2][16];    // 4 KB
  int t = threadIdx.x;

  if (blockIdx.x < SCATTER_BLOCKS) {
    int e = blockIdx.x * 256 + t;          // exact coverage
    int s = src[e];
    int d = dst[e];
    float wv = weight[e];
    unsigned int wq = (unsigned int)__float2int_rn(wv * 2047.0f) & 2047u;
    unsigned int rec = ((unsigned int)s << 16) | ((unsigned int)(d & 31) << 11) | wq;
    int bin = d >> 5;
    int pos = atomicAdd(&cursor[bin], 1);
    if (pos < BIN_CAP) payload[(size_t)bin * BIN_CAP + pos] = rec;
    return;
  }

  // ---- fc role ----
  int n0 = (blockIdx.x - SCATTER_BLOCKS) * FC_NODES_PER_BLOCK;
  for (int i = t; i < 512; i += 256)
    ((float4*)Wl)[i] = ((const float4*)Wfc)[i];
  {  // stage h: all 256 threads issue one coalesced float4
    int ns = t >> 5, r5 = t & 31, sb = r5 >> 4, i4 = r5 & 15;
    hs4[ns][sb][i4] = ((const float4*)h)[((size_t)sb * N_NODES + (n0 + ns)) * 16 + i4];
  }
  __syncthreads();
  int w = t >> 6, lane = t & 63, o = lane & 31, b = lane >> 5;
  int nsA = 2 * w, nsB = nsA + 1;
  float bo = bfc[o];
  float accA = bo, accB = bo;
#pragma unroll
  for (int i4 = 0; i4 < 16; ++i4) {
    float4 hA = hs4[nsA][b][i4];
    float4 hB = hs4[nsB][b][i4];
    float w0 = Wl[(i4 * 4 + 0) * OUT_DIM + o];
    float w1 = Wl[(i4 * 4 + 1) * OUT_DIM + o];
    float w2 = Wl[(i4 * 4 + 2) * OUT_DIM + o];
    float w3 = Wl[(i4 * 4 + 3) * OUT_DIM + o];
    accA = fmaf(hA.x, w0, accA); accA = fmaf(hA.y, w1, accA);
    accA = fmaf(hA.z, w2, accA); accA = fmaf(hA.w, w3, accA);
    accB = fmaf(hB.x, w0, accB); accB = fmaf(hB.y, w1, accB);
    accB = fmaf(hB.z, w2, accB); accB = fmaf(hB.w, w3, accB);
  }
  int nA = n0 + nsA, nB = n0 + nsB;
  ezh[(size_t)nA * FEAT + lane] = __float2half(__expf(accA));
  ezh[(size_t)nB * FEAT + lane] = __float2half(__expf(accB));
  float wo1 = Watt[o], wo2 = Watt[OUT_DIM + o];
  float psA = accA * wo1, pdA = accA * wo2;
  float psB = accB * wo1, pdB = accB * wo2;
#pragma unroll
  for (int m = 16; m >= 1; m >>= 1) {
    psA += __shfl_xor(psA, m, 64); pdA += __shfl_xor(pdA, m, 64);
    psB += __shfl_xor(psB, m, 64); pdB += __shfl_xor(pdB, m, 64);
  }
  if (o == 0) {
    ((float2*)(a_tab + nA))[b] = make_float2(psA, pdA);
    ((float2*)(a_tab + nB))[b] = make_float2(psB, pdB);
  }
}

// K2: one block per bin. num/den for 32 nodes live in 16 KB LDS; each wave
// streams its quarter of the bin's records with a 4-deep gather pipeline.
__global__ __launch_bounds__(256) void accum_kernel(
    const __half* __restrict__ ezh, const unsigned int* __restrict__ payload,
    const int* __restrict__ cursor, const float* __restrict__ a_tab,
    const float* __restrict__ Watt, const float* __restrict__ batt,
    float* __restrict__ out) {
  __shared__ float nm[NODES_PER_BIN * FEAT];   // 8 KB
  __shared__ float dn[NODES_PER_BIN * FEAT];   // 8 KB
  int t = threadIdx.x;
  int bin = blockIdx.x;
  for (int i = t; i < NODES_PER_BIN * FEAT; i += 256) { nm[i] = 0.f; dn[i] = 0.f; }
  __syncthreads();
  int cnt = cursor[bin];
  cnt = cnt > BIN_CAP ? BIN_CAP : cnt;
  const unsigned int* seg = payload + (size_t)bin * BIN_CAP;
  int w = t >> 6, lane = t & 63, o = lane & 31, b = lane >> 5;
  float wA = Watt[2 * OUT_DIM];
  float bA = batt[0];
  const float kInvQ = 1.0f / 2047.0f;
  int nbase4 = bin * NODES_PER_BIN * 4 + b * 2 + 1;  // a_d[n,b] index base

  int i = w;
  for (; i + 12 < cnt; i += 16) {
    unsigned int r0 = seg[i], r1 = seg[i + 4], r2 = seg[i + 8], r3 = seg[i + 12];
    int s0 = r0 >> 16, s1 = r1 >> 16, s2 = r2 >> 16, s3 = r3 >> 16;
    float ez0 = __half2float(ezh[(size_t)s0 * FEAT + lane]);
    float ez1 = __half2float(ezh[(size_t)s1 * FEAT + lane]);
    float ez2 = __half2float(ezh[(size_t)s2 * FEAT + lane]);
    float ez3 = __half2float(ezh[(size_t)s3 * FEAT + lane]);
    int nl0 = (r0 >> 11) & 31, nl1 = (r1 >> 11) & 31;
    int nl2 = (r2 >> 11) & 31, nl3 = (r3 >> 11) & 31;
    float l0 = a_tab[s0 * 4 + b * 2] + a_tab[nbase4 + nl0 * 4] + fmaf((r0 & 2047u) * kInvQ, wA, bA);
    float l1 = a_tab[s1 * 4 + b * 2] + a_tab[nbase4 + nl1 * 4] + fmaf((r1 & 2047u) * kInvQ, wA, bA);
    float l2 = a_tab[s2 * 4 + b * 2] + a_tab[nbase4 + nl2 * 4] + fmaf((r2 & 2047u) * kInvQ, wA, bA);
    float l3 = a_tab[s3 * 4 + b * 2] + a_tab[nbase4 + nl3 * 4] + fmaf((r3 & 2047u) * kInvQ, wA, bA);
    l0 = l0 > 0.f ? l0 : 0.01f * l0;
    l1 = l1 > 0.f ? l1 : 0.01f * l1;
    l2 = l2 > 0.f ? l2 : 0.01f * l2;
    l3 = l3 > 0.f ? l3 : 0.01f * l3;
    atomicAdd(&nm[nl0 * FEAT + lane], ez0 * l0); atomicAdd(&dn[nl0 * FEAT + lane], ez0);
    atomicAdd(&nm[nl1 * FEAT + lane], ez1 * l1); atomicAdd(&dn[nl1 * FEAT + lane], ez1);
    atomicAdd(&nm[nl2 * FEAT + lane], ez2 * l2); atomicAdd(&dn[nl2 * FEAT + lane], ez2);
    atomicAdd(&nm[nl3 * FEAT + lane], ez3 * l3); atomicAdd(&dn[nl3 * FEAT + lane], ez3);
  }
  for (; i < cnt; i += 4) {
    unsigned int r = seg[i];
    int s = r >> 16;
    int nl = (r >> 11) & 31;
    float ez = __half2float(ezh[(size_t)s * FEAT + lane]);
    float l = a_tab[s * 4 + b * 2] + a_tab[nbase4 + nl * 4] + fmaf((r & 2047u) * kInvQ, wA, bA);
    l = l > 0.f ? l : 0.01f * l;
    atomicAdd(&nm[nl * FEAT + lane], ez * l);
    atomicAdd(&dn[nl * FEAT + lane], ez);
  }
  __syncthreads();
  // epilogue: 32 nodes x 64 feats = 2048 values, 8 per thread; flat = nl*64+l2
#pragma unroll
  for (int k = 0; k < 8; ++k) {
    int flat = k * 256 + t;
    int nl = flat >> 6, l2 = flat & 63, oo = l2 & 31, bb = l2 >> 5;
    int n = bin * NODES_PER_BIN + nl;
    if (n < N_NODES) {
      float d = dn[flat];
      float v = (d > 0.f) ? nm[flat] / d : 0.f;
      out[((size_t)bb * N_NODES + n) * OUT_DIM + oo] = v;
    }
  }
}

extern "C" void kernel_launch(void* const* d_in, const int* in_sizes, int n_in,
                              void* d_out, int out_size, void* d_ws, size_t ws_size,
                              hipStream_t stream) {
  const float* h      = (const float*)d_in[0];
  const float* weight = (const float*)d_in[1];
  const int*   src    = (const int*)d_in[2];
  const int*   dst    = (const int*)d_in[3];
  const float* Wfc    = (const float*)d_in[4];
  const float* bfc    = (const float*)d_in[5];
  const float* Watt   = (const float*)d_in[6];
  const float* batt   = (const float*)d_in[7];
  float* out = (float*)d_out;

  // workspace (~12 MB)
  float4*       a_tab   = (float4*)d_ws;                              // 800 KB
  unsigned int* payload = (unsigned int*)(a_tab + N_NODES);           // NBINS*BIN_CAP*4 ~ 4.8 MB
  __half*       ezh     = (__half*)(payload + (size_t)NBINS * BIN_CAP); // 6.4 MB
  int*          cursor  = (int*)(ezh + (size_t)N_NODES * FEAT);       // ~6.3 KB

  hipMemsetAsync(cursor, 0, NBINS * sizeof(int), stream);
  fused_fc_scatter_kernel<<<SCATTER_BLOCKS + FC_BLOCKS, 256, 0, stream>>>(
      h, Wfc, bfc, Watt, src, dst, weight, ezh, a_tab, cursor, payload);
  accum_kernel<<<NBINS, 256, 0, stream>>>(ezh, payload, cursor,
                                          (const float*)a_tab, Watt, batt, out);
}

// Round 6
// 256.828 us; speedup vs baseline: 3.2214x; 3.2214x over previous
//
#include <hip/hip_runtime.h>
#include <hip/hip_fp16.h>

#define N_NODES 50000
#define N_EDGES 800000
#define IN_DIM  64
#define OUT_DIM 32
#define FEAT    64                   // B*OUT per node, node-major [N][B][OUT]
#define NODES_PER_BIN 32
#define NBINS   ((N_NODES + NODES_PER_BIN - 1) / NODES_PER_BIN)   // 1563
#define BIN_CAP 768                  // mean 512, sigma ~23 -> +11 sigma
#define SCATTER_BLOCKS (N_EDGES / 256)            // 3125 (exact)
#define FC_NODES_PER_BLOCK 8
#define FC_BLOCKS (N_NODES / FC_NODES_PER_BLOCK)  // 6250 (exact)

// Fused K1 (unchanged from R5 — binned scatter writes hit ~1563 hot L2 lines).
//  Record: src(16b) | dst&31 (5b) | weight quantized to 11b.
__global__ __launch_bounds__(256) void fused_fc_scatter_kernel(
    const float* __restrict__ h, const float* __restrict__ Wfc,
    const float* __restrict__ bfc, const float* __restrict__ Watt,
    const int* __restrict__ src, const int* __restrict__ dst,
    const float* __restrict__ weight,
    __half* __restrict__ ezh, float4* __restrict__ a_tab,
    int* __restrict__ cursor, unsigned int* __restrict__ payload) {
  __shared__ float Wl[IN_DIM * OUT_DIM];               // 8 KB
  __shared__ float4 hs4[FC_NODES_PER_BLOCK][2][16];    // 4 KB
  int t = threadIdx.x;

  if (blockIdx.x < SCATTER_BLOCKS) {
    int e = blockIdx.x * 256 + t;          // exact coverage
    int s = src[e];
    int d = dst[e];
    float wv = weight[e];
    unsigned int wq = (unsigned int)__float2int_rn(wv * 2047.0f) & 2047u;
    unsigned int rec = ((unsigned int)s << 16) | ((unsigned int)(d & 31) << 11) | wq;
    int bin = d >> 5;
    int pos = atomicAdd(&cursor[bin], 1);
    if (pos < BIN_CAP) payload[(size_t)bin * BIN_CAP + pos] = rec;
    return;
  }

  // ---- fc role ----
  int n0 = (blockIdx.x - SCATTER_BLOCKS) * FC_NODES_PER_BLOCK;
  for (int i = t; i < 512; i += 256)
    ((float4*)Wl)[i] = ((const float4*)Wfc)[i];
  {  // stage h: all 256 threads issue one coalesced float4
    int ns = t >> 5, r5 = t & 31, sb = r5 >> 4, i4 = r5 & 15;
    hs4[ns][sb][i4] = ((const float4*)h)[((size_t)sb * N_NODES + (n0 + ns)) * 16 + i4];
  }
  __syncthreads();
  int w = t >> 6, lane = t & 63, o = lane & 31, b = lane >> 5;
  int nsA = 2 * w, nsB = nsA + 1;
  float bo = bfc[o];
  float accA = bo, accB = bo;
#pragma unroll
  for (int i4 = 0; i4 < 16; ++i4) {
    float4 hA = hs4[nsA][b][i4];
    float4 hB = hs4[nsB][b][i4];
    float w0 = Wl[(i4 * 4 + 0) * OUT_DIM + o];
    float w1 = Wl[(i4 * 4 + 1) * OUT_DIM + o];
    float w2 = Wl[(i4 * 4 + 2) * OUT_DIM + o];
    float w3 = Wl[(i4 * 4 + 3) * OUT_DIM + o];
    accA = fmaf(hA.x, w0, accA); accA = fmaf(hA.y, w1, accA);
    accA = fmaf(hA.z, w2, accA); accA = fmaf(hA.w, w3, accA);
    accB = fmaf(hB.x, w0, accB); accB = fmaf(hB.y, w1, accB);
    accB = fmaf(hB.z, w2, accB); accB = fmaf(hB.w, w3, accB);
  }
  int nA = n0 + nsA, nB = n0 + nsB;
  ezh[(size_t)nA * FEAT + lane] = __float2half(__expf(accA));
  ezh[(size_t)nB * FEAT + lane] = __float2half(__expf(accB));
  float wo1 = Watt[o], wo2 = Watt[OUT_DIM + o];
  float psA = accA * wo1, pdA = accA * wo2;
  float psB = accB * wo1, pdB = accB * wo2;
#pragma unroll
  for (int m = 16; m >= 1; m >>= 1) {
    psA += __shfl_xor(psA, m, 64); pdA += __shfl_xor(pdA, m, 64);
    psB += __shfl_xor(psB, m, 64); pdB += __shfl_xor(pdB, m, 64);
  }
  if (o == 0) {
    ((float2*)(a_tab + nA))[b] = make_float2(psA, pdA);
    ((float2*)(a_tab + nB))[b] = make_float2(psB, pdB);
  }
}

// K2 v2: per-bin counting sort in LDS (integer atomics only), then each wave
// owns 8 nodes and accumulates num/den in REGISTERS (no f32 LDS atomics).
__global__ __launch_bounds__(256) void accum_kernel(
    const __half* __restrict__ ezh, const unsigned int* __restrict__ payload,
    const int* __restrict__ cursor, const float* __restrict__ a_tab,
    const float* __restrict__ Watt, const float* __restrict__ batt,
    float* __restrict__ out) {
  __shared__ unsigned int rec[BIN_CAP];     // 3 KB
  __shared__ unsigned int sorted[BIN_CAP];  // 3 KB
  __shared__ int hist[NODES_PER_BIN];
  __shared__ int off[NODES_PER_BIN];
  __shared__ int cnt2[NODES_PER_BIN];
  int t = threadIdx.x;
  int bin = blockIdx.x;
  if (t < NODES_PER_BIN) { hist[t] = 0; cnt2[t] = 0; }
  __syncthreads();
  int cnt = cursor[bin];
  cnt = cnt > BIN_CAP ? BIN_CAP : cnt;
  const unsigned int* seg = payload + (size_t)bin * BIN_CAP;
  for (int i = t; i < cnt; i += 256) {
    unsigned int r = seg[i];
    rec[i] = r;
    atomicAdd(&hist[(r >> 11) & 31], 1);    // native int LDS atomic
  }
  __syncthreads();
  // exclusive scan of the 32 counts by wave 0 (shuffle scan)
  if (t < 64) {
    int v = (t < 32) ? hist[t] : 0;
    int orig = v;
#pragma unroll
    for (int d = 1; d < 32; d <<= 1) {
      int x = __shfl_up(v, d, 64);
      if (t >= d) v += x;
    }
    if (t < 32) off[t] = v - orig;
  }
  __syncthreads();
  for (int i = t; i < cnt; i += 256) {
    unsigned int r = rec[i];
    int nl = (r >> 11) & 31;
    int pos = off[nl] + atomicAdd(&cnt2[nl], 1);
    sorted[pos] = r;
  }
  __syncthreads();

  int w = t >> 6, lane = t & 63, o = lane & 31, b = lane >> 5;
  float wA = Watt[2 * OUT_DIM];
  float bA = batt[0];
  const float kInvQ = 1.0f / 2047.0f;
#pragma unroll
  for (int k = 0; k < 8; ++k) {
    int nl = w * 8 + k;                     // wave-uniform
    int n = bin * NODES_PER_BIN + nl;
    if (n >= N_NODES) break;
    int cn = hist[nl];
    int base = off[nl];
    float adst = a_tab[n * 4 + b * 2 + 1];  // a_d[n,b]
    float num = 0.f, den = 0.f;
    int i = 0;
    for (; i + 3 < cn; i += 4) {
      unsigned int r0 = sorted[base + i],     r1 = sorted[base + i + 1];
      unsigned int r2 = sorted[base + i + 2], r3 = sorted[base + i + 3];
      int s0 = r0 >> 16, s1 = r1 >> 16, s2 = r2 >> 16, s3 = r3 >> 16;
      float ez0 = __half2float(ezh[(size_t)s0 * FEAT + lane]);
      float ez1 = __half2float(ezh[(size_t)s1 * FEAT + lane]);
      float ez2 = __half2float(ezh[(size_t)s2 * FEAT + lane]);
      float ez3 = __half2float(ezh[(size_t)s3 * FEAT + lane]);
      float l0 = a_tab[s0 * 4 + b * 2] + adst + fmaf((r0 & 2047u) * kInvQ, wA, bA);
      float l1 = a_tab[s1 * 4 + b * 2] + adst + fmaf((r1 & 2047u) * kInvQ, wA, bA);
      float l2 = a_tab[s2 * 4 + b * 2] + adst + fmaf((r2 & 2047u) * kInvQ, wA, bA);
      float l3 = a_tab[s3 * 4 + b * 2] + adst + fmaf((r3 & 2047u) * kInvQ, wA, bA);
      l0 = l0 > 0.f ? l0 : 0.01f * l0;
      l1 = l1 > 0.f ? l1 : 0.01f * l1;
      l2 = l2 > 0.f ? l2 : 0.01f * l2;
      l3 = l3 > 0.f ? l3 : 0.01f * l3;
      num = fmaf(ez0, l0, num); den += ez0;
      num = fmaf(ez1, l1, num); den += ez1;
      num = fmaf(ez2, l2, num); den += ez2;
      num = fmaf(ez3, l3, num); den += ez3;
    }
    for (; i < cn; ++i) {
      unsigned int r = sorted[base + i];
      int s = r >> 16;
      float ez = __half2float(ezh[(size_t)s * FEAT + lane]);
      float l = a_tab[s * 4 + b * 2] + adst + fmaf((r & 2047u) * kInvQ, wA, bA);
      l = l > 0.f ? l : 0.01f * l;
      num = fmaf(ez, l, num); den += ez;
    }
    float v = (cn > 0) ? num / den : 0.f;
    out[((size_t)b * N_NODES + n) * OUT_DIM + o] = v;
  }
}

extern "C" void kernel_launch(void* const* d_in, const int* in_sizes, int n_in,
                              void* d_out, int out_size, void* d_ws, size_t ws_size,
                              hipStream_t stream) {
  const float* h      = (const float*)d_in[0];
  const float* weight = (const float*)d_in[1];
  const int*   src    = (const int*)d_in[2];
  const int*   dst    = (const int*)d_in[3];
  const float* Wfc    = (const float*)d_in[4];
  const float* bfc    = (const float*)d_in[5];
  const float* Watt   = (const float*)d_in[6];
  const float* batt   = (const float*)d_in[7];
  float* out = (float*)d_out;

  // workspace (~12 MB)
  float4*       a_tab   = (float4*)d_ws;                              // 800 KB
  unsigned int* payload = (unsigned int*)(a_tab + N_NODES);           // ~4.8 MB
  __half*       ezh     = (__half*)(payload + (size_t)NBINS * BIN_CAP); // 6.4 MB
  int*          cursor  = (int*)(ezh + (size_t)N_NODES * FEAT);       // ~6.3 KB

  hipMemsetAsync(cursor, 0, NBINS * sizeof(int), stream);
  fused_fc_scatter_kernel<<<SCATTER_BLOCKS + FC_BLOCKS, 256, 0, stream>>>(
      h, Wfc, bfc, Watt, src, dst, weight, ezh, a_tab, cursor, payload);
  accum_kernel<<<NBINS, 256, 0, stream>>>(ezh, payload, cursor,
                                          (const float*)a_tab, Watt, batt, out);
}

// Round 7
// 180.367 us; speedup vs baseline: 4.5870x; 1.4239x over previous
//
#include <hip/hip_runtime.h>
#include <hip/hip_fp16.h>

#define N_NODES 50000
#define N_EDGES 800000
#define IN_DIM  64
#define OUT_DIM 32
#define FEAT    64                   // B*OUT per node, node-major [N][B][OUT]
#define NODES_PER_BIN 32
#define NBINS   ((N_NODES + NODES_PER_BIN - 1) / NODES_PER_BIN)   // 1563
#define NCLS    8                    // XCD classes (blockIdx & 7)
#define CLS_CAP 128                  // per (bin,class): mean 64, P(>=128) ~ 2e-11
#define BIN_SLOTS (NCLS * CLS_CAP)   // 1024 slots per bin
#define SCATTER_BLOCKS (N_EDGES / 256)            // 3125 (exact)
#define FC_NODES_PER_BLOCK 8
#define FC_BLOCKS (N_NODES / FC_NODES_PER_BLOCK)  // 6250 (exact)

// Fused K1.
//  Scatter role: bin = dst>>5, class = blockIdx&7. Round-robin dispatch puts
//  same-class blocks on the same XCD, so each (bin,class) frontier line is
//  written by ONE XCD's L2 only — kills R6's 8x cross-XCD write amplification.
//  Per-class edge counts are exactly N_EDGES/8 by construction (hardware-
//  independent overflow bound). Record: src(16b) | dst&31 (5b) | w_q11.
//  FC role: unchanged from R6.
__global__ __launch_bounds__(256) void fused_fc_scatter_kernel(
    const float* __restrict__ h, const float* __restrict__ Wfc,
    const float* __restrict__ bfc, const float* __restrict__ Watt,
    const int* __restrict__ src, const int* __restrict__ dst,
    const float* __restrict__ weight,
    __half* __restrict__ ezh, float4* __restrict__ a_tab,
    int* __restrict__ cursor, unsigned int* __restrict__ payload) {
  __shared__ float Wl[IN_DIM * OUT_DIM];               // 8 KB
  __shared__ float4 hs4[FC_NODES_PER_BLOCK][2][16];    // 4 KB
  int t = threadIdx.x;

  if (blockIdx.x < SCATTER_BLOCKS) {
    int e = blockIdx.x * 256 + t;          // exact coverage
    int cls = blockIdx.x & 7;
    int s = src[e];
    int d = dst[e];
    float wv = weight[e];
    unsigned int wq = (unsigned int)__float2int_rn(wv * 2047.0f) & 2047u;
    unsigned int rec = ((unsigned int)s << 16) | ((unsigned int)(d & 31) << 11) | wq;
    int bin = d >> 5;
    int pos = atomicAdd(&cursor[bin * NCLS + cls], 1);
    if (pos < CLS_CAP)
      payload[(size_t)bin * BIN_SLOTS + cls * CLS_CAP + pos] = rec;
    return;
  }

  // ---- fc role ----
  int n0 = (blockIdx.x - SCATTER_BLOCKS) * FC_NODES_PER_BLOCK;
  for (int i = t; i < 512; i += 256)
    ((float4*)Wl)[i] = ((const float4*)Wfc)[i];
  {  // stage h: all 256 threads issue one coalesced float4
    int ns = t >> 5, r5 = t & 31, sb = r5 >> 4, i4 = r5 & 15;
    hs4[ns][sb][i4] = ((const float4*)h)[((size_t)sb * N_NODES + (n0 + ns)) * 16 + i4];
  }
  __syncthreads();
  int w = t >> 6, lane = t & 63, o = lane & 31, b = lane >> 5;
  int nsA = 2 * w, nsB = nsA + 1;
  float bo = bfc[o];
  float accA = bo, accB = bo;
#pragma unroll
  for (int i4 = 0; i4 < 16; ++i4) {
    float4 hA = hs4[nsA][b][i4];
    float4 hB = hs4[nsB][b][i4];
    float w0 = Wl[(i4 * 4 + 0) * OUT_DIM + o];
    float w1 = Wl[(i4 * 4 + 1) * OUT_DIM + o];
    float w2 = Wl[(i4 * 4 + 2) * OUT_DIM + o];
    float w3 = Wl[(i4 * 4 + 3) * OUT_DIM + o];
    accA = fmaf(hA.x, w0, accA); accA = fmaf(hA.y, w1, accA);
    accA = fmaf(hA.z, w2, accA); accA = fmaf(hA.w, w3, accA);
    accB = fmaf(hB.x, w0, accB); accB = fmaf(hB.y, w1, accB);
    accB = fmaf(hB.z, w2, accB); accB = fmaf(hB.w, w3, accB);
  }
  int nA = n0 + nsA, nB = n0 + nsB;
  ezh[(size_t)nA * FEAT + lane] = __float2half(__expf(accA));
  ezh[(size_t)nB * FEAT + lane] = __float2half(__expf(accB));
  float wo1 = Watt[o], wo2 = Watt[OUT_DIM + o];
  float psA = accA * wo1, pdA = accA * wo2;
  float psB = accB * wo1, pdB = accB * wo2;
#pragma unroll
  for (int m = 16; m >= 1; m >>= 1) {
    psA += __shfl_xor(psA, m, 64); pdA += __shfl_xor(pdA, m, 64);
    psB += __shfl_xor(psB, m, 64); pdB += __shfl_xor(pdB, m, 64);
  }
  if (o == 0) {
    ((float2*)(a_tab + nA))[b] = make_float2(psA, pdA);
    ((float2*)(a_tab + nB))[b] = make_float2(psB, pdB);
  }
}

// K2: 4 blocks per bin (quad = blockIdx&3 owns 8 of the bin's 32 nodes).
// Each block counting-sorts the bin's valid records in LDS (int atomics only),
// then each wave register-accumulates 2 nodes. 6252 blocks => ~24/CU queued.
__global__ __launch_bounds__(256) void accum_kernel(
    const __half* __restrict__ ezh, const unsigned int* __restrict__ payload,
    const int* __restrict__ cursor, const float* __restrict__ a_tab,
    const float* __restrict__ Watt, const float* __restrict__ batt,
    float* __restrict__ out) {
  __shared__ unsigned int rec[BIN_SLOTS];     // 4 KB (raw slots, some invalid)
  __shared__ unsigned int sorted[BIN_SLOTS];  // 4 KB
  __shared__ int c8[NCLS];
  __shared__ int hist[NODES_PER_BIN];
  __shared__ int off[NODES_PER_BIN];
  __shared__ int cnt2[NODES_PER_BIN];
  int t = threadIdx.x;
  int bin = blockIdx.x >> 2;
  int quad = blockIdx.x & 3;
  if (t < NCLS) {
    int c = cursor[bin * NCLS + t];
    c8[t] = c > CLS_CAP ? CLS_CAP : c;
  }
  if (t < NODES_PER_BIN) { hist[t] = 0; cnt2[t] = 0; }
  __syncthreads();
  const unsigned int* seg = payload + (size_t)bin * BIN_SLOTS;
  for (int j = t; j < BIN_SLOTS; j += 256) {
    unsigned int r = seg[j];
    rec[j] = r;
    if ((j & (CLS_CAP - 1)) < c8[j >> 7])          // slot valid?
      atomicAdd(&hist[(r >> 11) & 31], 1);
  }
  __syncthreads();
  if (t < 64) {  // exclusive scan of 32 counts (wave 0 shuffle scan)
    int v = (t < 32) ? hist[t] : 0;
    int orig = v;
#pragma unroll
    for (int d = 1; d < 32; d <<= 1) {
      int x = __shfl_up(v, d, 64);
      if (t >= d) v += x;
    }
    if (t < 32) off[t] = v - orig;
  }
  __syncthreads();
  for (int j = t; j < BIN_SLOTS; j += 256) {
    if ((j & (CLS_CAP - 1)) < c8[j >> 7]) {
      unsigned int r = rec[j];
      int nl = (r >> 11) & 31;
      sorted[off[nl] + atomicAdd(&cnt2[nl], 1)] = r;
    }
  }
  __syncthreads();

  int w = t >> 6, lane = t & 63, o = lane & 31, b = lane >> 5;
  float wA = Watt[2 * OUT_DIM];
  float bA = batt[0];
  const float kInvQ = 1.0f / 2047.0f;
#pragma unroll
  for (int k = 0; k < 2; ++k) {
    int nl = quad * 8 + w * 2 + k;              // wave-uniform, this block's range
    int n = bin * NODES_PER_BIN + nl;
    if (n >= N_NODES) break;
    int cn = hist[nl];
    int base = off[nl];
    float adst = a_tab[n * 4 + b * 2 + 1];      // a_d[n,b]
    float num = 0.f, den = 0.f;
    int i = 0;
    for (; i + 3 < cn; i += 4) {
      unsigned int r0 = sorted[base + i],     r1 = sorted[base + i + 1];
      unsigned int r2 = sorted[base + i + 2], r3 = sorted[base + i + 3];
      int s0 = r0 >> 16, s1 = r1 >> 16, s2 = r2 >> 16, s3 = r3 >> 16;
      float ez0 = __half2float(ezh[(size_t)s0 * FEAT + lane]);
      float ez1 = __half2float(ezh[(size_t)s1 * FEAT + lane]);
      float ez2 = __half2float(ezh[(size_t)s2 * FEAT + lane]);
      float ez3 = __half2float(ezh[(size_t)s3 * FEAT + lane]);
      float l0 = a_tab[s0 * 4 + b * 2] + adst + fmaf((r0 & 2047u) * kInvQ, wA, bA);
      float l1 = a_tab[s1 * 4 + b * 2] + adst + fmaf((r1 & 2047u) * kInvQ, wA, bA);
      float l2 = a_tab[s2 * 4 + b * 2] + adst + fmaf((r2 & 2047u) * kInvQ, wA, bA);
      float l3 = a_tab[s3 * 4 + b * 2] + adst + fmaf((r3 & 2047u) * kInvQ, wA, bA);
      l0 = l0 > 0.f ? l0 : 0.01f * l0;
      l1 = l1 > 0.f ? l1 : 0.01f * l1;
      l2 = l2 > 0.f ? l2 : 0.01f * l2;
      l3 = l3 > 0.f ? l3 : 0.01f * l3;
      num = fmaf(ez0, l0, num); den += ez0;
      num = fmaf(ez1, l1, num); den += ez1;
      num = fmaf(ez2, l2, num); den += ez2;
      num = fmaf(ez3, l3, num); den += ez3;
    }
    for (; i < cn; ++i) {
      unsigned int r = sorted[base + i];
      int s = r >> 16;
      float ez = __half2float(ezh[(size_t)s * FEAT + lane]);
      float l = a_tab[s * 4 + b * 2] + adst + fmaf((r & 2047u) * kInvQ, wA, bA);
      l = l > 0.f ? l : 0.01f * l;
      num = fmaf(ez, l, num); den += ez;
    }
    float v = (cn > 0) ? num / den : 0.f;
    out[((size_t)b * N_NODES + n) * OUT_DIM + o] = v;
  }
}

extern "C" void kernel_launch(void* const* d_in, const int* in_sizes, int n_in,
                              void* d_out, int out_size, void* d_ws, size_t ws_size,
                              hipStream_t stream) {
  const float* h      = (const float*)d_in[0];
  const float* weight = (const float*)d_in[1];
  const int*   src    = (const int*)d_in[2];
  const int*   dst    = (const int*)d_in[3];
  const float* Wfc    = (const float*)d_in[4];
  const float* bfc    = (const float*)d_in[5];
  const float* Watt   = (const float*)d_in[6];
  const float* batt   = (const float*)d_in[7];
  float* out = (float*)d_out;

  // workspace (~13.7 MB)
  float4*       a_tab   = (float4*)d_ws;                                // 800 KB
  unsigned int* payload = (unsigned int*)(a_tab + N_NODES);             // NBINS*1024*4 = 6.4 MB
  __half*       ezh     = (__half*)(payload + (size_t)NBINS * BIN_SLOTS); // 6.4 MB
  int*          cursor  = (int*)(ezh + (size_t)N_NODES * FEAT);         // ~50 KB

  hipMemsetAsync(cursor, 0, NBINS * NCLS * sizeof(int), stream);
  fused_fc_scatter_kernel<<<SCATTER_BLOCKS + FC_BLOCKS, 256, 0, stream>>>(
      h, Wfc, bfc, Watt, src, dst, weight, ezh, a_tab, cursor, payload);
  accum_kernel<<<NBINS * 4, 256, 0, stream>>>(ezh, payload, cursor,
                                              (const float*)a_tab, Watt, batt, out);
}